// Round 1
// baseline (574.007 us; speedup 1.0000x reference)
//
#include <hip/hip_runtime.h>

#define NEGV -10000.0f
constexpr int K  = 128;   // states
constexpr int T  = 512;   // timesteps
constexpr int CH = 8;     // h-prefetch chunk (timesteps)

// s_barrier WITHOUT the compiler's vmcnt(0) drain: waits LDS ops only,
// leaves async global_load_lds prefetch in flight across the barrier.
__device__ __forceinline__ void bar_lgkm() {
  asm volatile("s_waitcnt lgkmcnt(0)\n\ts_barrier" ::: "memory");
}
__device__ __forceinline__ void wait_vm0() {
  asm volatile("s_waitcnt vmcnt(0)" ::: "memory");
}
// async global -> LDS, 16B per lane; LDS dest = wave-uniform base + lane*16
__device__ __forceinline__ void dma16(const float* g, float* l) {
  __builtin_amdgcn_global_load_lds(
      (const __attribute__((address_space(1))) void*)g,
      (__attribute__((address_space(3))) void*)l, 16, 0, 0);
}

__global__ __launch_bounds__(256, 1)
void crf_fwd(const float* __restrict__ h, const float* __restrict__ trans,
             const float* __restrict__ mask, float* __restrict__ out) {
  const int tid  = threadIdx.x;
  const int b    = blockIdx.x;
  const int j    = tid & (K - 1);   // state this thread owns
  const int half = tid >> 7;        // which 64-wide k-slice of the dot
  const int wid  = tid >> 6;
  const int lane = tid & 63;

  __shared__ __align__(16) float p_lds[K];
  __shared__ __align__(16) float partial[256];
  __shared__ __align__(16) float hbuf[2][CH * K];
  __shared__ float wmax[4];
  __shared__ float red[8];

  // ---- len = sum(mask[b,:]) (mask is a contiguous prefix of 1s) ----
  float msum = mask[b * T + tid] + mask[b * T + 256 + tid];
  #pragma unroll
  for (int off = 32; off > 0; off >>= 1) msum += __shfl_xor(msum, off);
  if (lane == 0) red[wid] = msum;

  // ---- E fragment in registers: E[j, half*64 + 0..63] = exp(trans[...]) ----
  float4 ef[16];
  const float4* tr4 = reinterpret_cast<const float4*>(trans + j * K + half * 64);
  #pragma unroll
  for (int i = 0; i < 16; ++i) {
    float4 v = tr4[i];
    ef[i] = make_float4(__expf(v.x), __expf(v.y), __expf(v.z), __expf(v.w));
  }
  const float tr_eos = trans[1 * K + j];  // trans[EOS_IDX=1, j]

  // ---- async prefetch of h chunk 0 (rows 0..7) into hbuf[0] ----
  const float* hb = h + (size_t)b * T * K;
  dma16(hb + wid * 256 + lane * 4, &hbuf[0][wid * 256]);

  if (tid < 4) wmax[tid] = 0.0f;   // max of init scores is exactly 0 (SOS)
  bar_lgkm();

  const int len = (int)(red[0] + red[1] + red[2] + red[3] + 0.5f);

  float score = (j == 0) ? 0.0f : NEGV;  // SOS_IDX = 0
  float Mcur  = 0.0f;                    // shift used this step (stale max, exact-canceling)
  int   cur   = 0;

  for (int t = 0; t < len; ++t) {
    const int cpos = t & (CH - 1);

    // phase 1: publish p_k = exp(score_k - M)
    if (tid < K) p_lds[j] = __expf(score - Mcur);
    bar_lgkm();                                   // barrier A

    if (cpos == 0) {                              // chunk boundary
      wait_vm0();                                 // chunk (t>>3) now resident
      cur = (t >> 3) & 1;
      const int tn = t + CH;
      if (tn < len) {                             // tn is then <= 504: in-bounds
        dma16(hb + (size_t)tn * K + wid * 256 + lane * 4,
              &hbuf[cur ^ 1][wid * 256]);
      }
    }
    // max of scores after step t-1 (written pre-A, visible now) -> used at t+1
    const float Mnext = fmaxf(fmaxf(wmax[0], wmax[1]), fmaxf(wmax[2], wmax[3]));

    // phase 2: half-dot  sum_k E[j,k] p_k  (p reads are all-lane broadcasts)
    const float4* p4 = reinterpret_cast<const float4*>(p_lds + half * 64);
    float a0 = 0.f, a1 = 0.f, a2 = 0.f, a3 = 0.f;
    #pragma unroll
    for (int i = 0; i < 16; ++i) {
      float4 pv = p4[i];
      a0 += ef[i].x * pv.x;
      a1 += ef[i].y * pv.y;
      a2 += ef[i].z * pv.z;
      a3 += ef[i].w * pv.w;
    }
    partial[tid] = (a0 + a1) + (a2 + a3);
    bar_lgkm();                                   // barrier B

    // phase 3: combine halves, update score (both halves compute identically)
    const float tot = partial[j] + partial[j + K];
    const float hv  = hbuf[cur][cpos * K + j];
    const float ns  = hv + Mcur + __logf(tot);
    score = ns;
    float wm = ns;
    #pragma unroll
    for (int off = 32; off > 0; off >>= 1) wm = fmaxf(wm, __shfl_xor(wm, off));
    if (lane == 0) wmax[wid] = wm;                // consumed after next barrier A
    Mcur = Mnext;
  }

  // ---- epilogue: out[b] = logsumexp_j(score_j + trans[EOS, j]) ----
  bar_lgkm();
  const float f = score + tr_eos;
  float m = f;
  #pragma unroll
  for (int off = 32; off > 0; off >>= 1) m = fmaxf(m, __shfl_xor(m, off));
  if (tid < K && lane == 0) red[wid] = m;         // waves 0,1 cover all 128 j
  bar_lgkm();
  const float fm = fmaxf(red[0], red[1]);
  float e = (tid < K) ? __expf(f - fm) : 0.0f;
  #pragma unroll
  for (int off = 32; off > 0; off >>= 1) e += __shfl_xor(e, off);
  if (tid < K && lane == 0) red[4 + wid] = e;
  bar_lgkm();
  if (tid == 0) out[b] = fm + __logf(red[4] + red[5]);
}

extern "C" void kernel_launch(void* const* d_in, const int* in_sizes, int n_in,
                              void* d_out, int out_size, void* d_ws, size_t ws_size,
                              hipStream_t stream) {
  const float* h     = (const float*)d_in[0];  // (B,T,K) fp32
  const float* trans = (const float*)d_in[1];  // (K,K)   fp32
  const float* mask  = (const float*)d_in[2];  // (B,T)   fp32
  float* out = (float*)d_out;                  // (B,)    fp32
  const int B = in_sizes[0] / (T * K);         // 256
  crf_fwd<<<B, 256, 0, stream>>>(h, trans, mask, out);
}

// Round 3
// 466.382 us; speedup vs baseline: 1.2308x; 1.2308x over previous
//
#include <hip/hip_runtime.h>

#define NEGV -10000.0f
constexpr int K  = 128;   // states
constexpr int T  = 512;   // timesteps
constexpr int CH = 8;     // h-prefetch chunk (timesteps)

// s_barrier WITHOUT the compiler's vmcnt(0) drain: waits LDS ops only,
// leaves async global_load_lds prefetch in flight across the barrier.
__device__ __forceinline__ void bar_lgkm() {
  asm volatile("s_waitcnt lgkmcnt(0)\n\ts_barrier" ::: "memory");
}
__device__ __forceinline__ void wait_vm0() {
  asm volatile("s_waitcnt vmcnt(0)" ::: "memory");
}
// async global -> LDS, 16B per lane; LDS dest = wave-uniform base + lane*16
__device__ __forceinline__ void dma16(const float* g, float* l) {
  __builtin_amdgcn_global_load_lds(
      (const __attribute__((address_space(1))) void*)g,
      (__attribute__((address_space(3))) void*)l, 16, 0, 0);
}

// One block = one batch row. 128 threads (2 waves), thread j owns state j.
// Linear-domain recurrence: tot_j = sum_k E[j,k] p_k ;  p'_j = tot_j * g_j
// with g_j = exp(h_j + S_t - S_{t+1}) computed OFF the critical path
// (h prefetched, S = tracker = score of state 2, 1 step stale).
// One barrier per step; p_lds and Mslot double-buffered against WAR races.
__global__ __launch_bounds__(128, 1)
void crf_fwd(const float* __restrict__ h, const float* __restrict__ trans,
             const float* __restrict__ mask, float* __restrict__ out) {
  const int tid  = threadIdx.x;    // 0..127
  const int b    = blockIdx.x;
  const int j    = tid;            // state owned
  const int wid  = tid >> 6;       // wave id 0/1
  const int lane = tid & 63;

  __shared__ __align__(16) float p_lds[2][K];          // double-buffered p
  __shared__ __align__(16) float hbuf[2][2][CH * 64];  // [buf][half][row*64+col]
  __shared__ float Mslot[2];                           // tracker, double-buffered
  __shared__ float red[4];

  // ---- len = sum(mask[b,:]) (contiguous prefix of 1s) ----
  float msum = 0.0f;
  #pragma unroll
  for (int i = 0; i < 4; ++i) msum += mask[b * T + i * 128 + tid];
  #pragma unroll
  for (int off = 32; off > 0; off >>= 1) msum += __shfl_xor(msum, off);
  if (lane == 0) red[wid] = msum;

  // ---- E row j in registers: E[j,k] = exp(trans[j,k]), k = 0..127 ----
  float4 ef[32];
  const float4* tr4 = reinterpret_cast<const float4*>(trans + j * K);
  #pragma unroll
  for (int i = 0; i < 32; ++i) {
    float4 v = tr4[i];
    ef[i] = make_float4(__expf(v.x), __expf(v.y), __expf(v.z), __expf(v.w));
  }
  const float tr_eos = trans[1 * K + j];  // trans[EOS_IDX=1, j]

  // ---- async prefetch of h chunk 0; wave w loads the half IT will read ----
  const float* hb = h + (size_t)b * T * K;
  {
    const float* g0 = hb + wid * 64;
    #pragma unroll
    for (int q = 0; q < 2; ++q)
      dma16(g0 + (size_t)(q * 4 + (lane >> 4)) * K + 4 * (lane & 15),
            &hbuf[0][wid][q * 256]);
  }

  // ---- init: p(0) = one-hot at SOS (exp(0)=1, exp(-1e4)=0) ----
  p_lds[0][j] = (j == 0) ? 1.0f : 0.0f;
  if (tid < 2) Mslot[tid] = 0.0f;
  bar_lgkm();

  const int len = (int)(red[0] + red[1] + 0.5f);

  float Scur = 0.0f;     // shift S_t that formed the p we are about to read
  float fs   = NEGV;     // true score of state j after the last step
  int   cur  = 0;

  for (int t = 0; t < len; ++t) {
    bar_lgkm();                          // p(t), Mslot writes now visible
    const int cpos = t & (CH - 1);
    const int rpar = t & 1;

    if (cpos == 0) {                     // chunk boundary: own DMA resident
      wait_vm0();
      cur = (t >> 3) & 1;
      const int tn = t + CH;
      if (tn < len) {
        const float* g0 = hb + (size_t)tn * K + wid * 64;
        #pragma unroll
        for (int q = 0; q < 2; ++q)
          dma16(g0 + (size_t)(q * 4 + (lane >> 4)) * K + 4 * (lane & 15),
                &hbuf[cur ^ 1][wid][q * 256]);
      }
    }

    const float Snext = Mslot[rpar ^ 1];              // S_{t+1} (1 step stale)
    const float hv    = hbuf[cur][wid][cpos * 64 + lane];

    // full 128-wide dot: tot_j = sum_k E[j,k] * p_k (broadcast reads)
    const float4* p4 = reinterpret_cast<const float4*>(p_lds[rpar]);
    float a0 = 0.f, a1 = 0.f, a2 = 0.f, a3 = 0.f;
    #pragma unroll
    for (int i = 0; i < 32; ++i) {
      float4 pv = p4[i];
      a0 += ef[i].x * pv.x;
      a1 += ef[i].y * pv.y;
      a2 += ef[i].z * pv.z;
      a3 += ef[i].w * pv.w;
    }
    const float tot = (a0 + a1) + (a2 + a3);

    // off-critical-path factor: g = exp(h + S_t - S_{t+1})
    const float g = __expf(hv + Scur - Snext);
    p_lds[rpar ^ 1][j] = tot * g;                     // p(t+1)

    fs = hv + Scur + __logf(tot);                     // true score_j(t)
    if (j == 2) Mslot[rpar] = fs;                     // tracker publish
    Scur = Snext;
  }

  // ---- epilogue: out[b] = logsumexp_j(fs_j + trans[EOS, j]) ----
  const float f = fs + tr_eos;
  float m = f;
  #pragma unroll
  for (int off = 32; off > 0; off >>= 1) m = fmaxf(m, __shfl_xor(m, off));
  if (lane == 0) red[wid] = m;
  bar_lgkm();
  const float fm = fmaxf(red[0], red[1]);
  float e = __expf(f - fm);
  #pragma unroll
  for (int off = 32; off > 0; off >>= 1) e += __shfl_xor(e, off);
  if (lane == 0) red[2 + wid] = e;
  bar_lgkm();
  if (tid == 0) out[b] = fm + __logf(red[2] + red[3]);
}

extern "C" void kernel_launch(void* const* d_in, const int* in_sizes, int n_in,
                              void* d_out, int out_size, void* d_ws, size_t ws_size,
                              hipStream_t stream) {
  const float* h     = (const float*)d_in[0];  // (B,T,K) fp32
  const float* trans = (const float*)d_in[1];  // (K,K)   fp32
  const float* mask  = (const float*)d_in[2];  // (B,T)   fp32
  float* out = (float*)d_out;                  // (B,)    fp32
  const int B = in_sizes[0] / (T * K);         // 256
  crf_fwd<<<B, 128, 0, stream>>>(h, trans, mask, out);
}

// Round 4
// 350.933 us; speedup vs baseline: 1.6357x; 1.3290x over previous
//
#include <hip/hip_runtime.h>

#define NEGV -10000.0f
constexpr int K  = 128;   // states
constexpr int T  = 512;   // timesteps
constexpr int CH = 8;     // h-prefetch chunk (timesteps)

// s_barrier WITHOUT the compiler's vmcnt(0) drain.
__device__ __forceinline__ void bar_lgkm() {
  asm volatile("s_waitcnt lgkmcnt(0)\n\ts_barrier" ::: "memory");
}
__device__ __forceinline__ void wait_vm0() {
  asm volatile("s_waitcnt vmcnt(0)" ::: "memory");
}
// async global -> LDS, 16B/lane; LDS dest = wave-uniform base + lane*16
__device__ __forceinline__ void dma16(const float* g, float* l) {
  __builtin_amdgcn_global_load_lds(
      (const __attribute__((address_space(1))) void*)g,
      (__attribute__((address_space(3))) void*)l, 16, 0, 0);
}
// add the quad-mate's value (lanes 2m <-> 2m+1): VALU DPP, no LDS pipe
__device__ __forceinline__ float pair_sum(float x) {
  int o = __builtin_amdgcn_update_dpp(0, __float_as_int(x), 0xB1, 0xF, 0xF, true);
  return x + __int_as_float(o);
}

// One block = one batch row. 256 threads (4 waves); thread = (j = tid>>1,
// half = tid&1); each thread holds HALF an E row (64 floats) in NAMED float4
// registers (no array -> no scratch spill, the R1/R3 killer). Linear-domain
// recurrence, one barrier/step, half-combine via DPP quad_perm add.
__global__ __launch_bounds__(256, 1)
void crf_fwd(const float* __restrict__ h, const float* __restrict__ trans,
             const float* __restrict__ mask, float* __restrict__ out) {
  const int tid  = threadIdx.x;    // 0..255
  const int b    = blockIdx.x;
  const int j    = tid >> 1;       // state owned (each j twice)
  const int half = tid & 1;        // which 64-wide k-slice
  const int wid  = tid >> 6;       // wave id 0..3
  const int lane = tid & 63;

  __shared__ __align__(16) float p_lds[2][K];          // double-buffered p
  __shared__ __align__(16) float hbuf[2][4][CH][32];   // [buf][wave][row][col]
  __shared__ float Mslot[2];                           // tracker, double-buffered
  __shared__ float red[8];

  // ---- len = sum(mask[b,:]) (contiguous prefix of 1s) ----
  float msum = mask[b * T + tid] + mask[b * T + 256 + tid];
  #pragma unroll
  for (int off = 32; off > 0; off >>= 1) msum += __shfl_xor(msum, off);
  if (lane == 0) red[wid] = msum;

  // ---- E half-row in NAMED registers: E[j, 64*half + k], k = 0..63 ----
  const float4* tr4 = reinterpret_cast<const float4*>(trans + j * K + 64 * half);
#define LDE(n) float4 e##n = tr4[n]; \
  e##n = make_float4(__expf(e##n.x), __expf(e##n.y), __expf(e##n.z), __expf(e##n.w));
  LDE(0)  LDE(1)  LDE(2)  LDE(3)  LDE(4)  LDE(5)  LDE(6)  LDE(7)
  LDE(8)  LDE(9)  LDE(10) LDE(11) LDE(12) LDE(13) LDE(14) LDE(15)
#undef LDE
  const float tr_eos = trans[1 * K + j];  // trans[EOS_IDX=1, j]

  // ---- async prefetch of h chunk 0; wave w loads its own j-slice ----
  // hbuf[buf][w][r][c] = h[t0+r, 32w+c]; one dma16/wave/chunk:
  // lane l -> row l>>3, cols 4*(l&7)..+3
  const float* hb = h + (size_t)b * T * K;
  dma16(hb + (size_t)(lane >> 3) * K + 32 * wid + 4 * (lane & 7),
        &hbuf[0][wid][0][0]);

  // ---- init: p(0) one-hot at SOS (both halves write same value) ----
  p_lds[0][j] = (j == 0) ? 1.0f : 0.0f;
  if (tid < 2) Mslot[tid] = 0.0f;
  bar_lgkm();

  const int len = (int)(red[0] + red[1] + red[2] + red[3] + 0.5f);

  float Scur = 0.0f;   // shift that formed the p we are about to read
  float fs   = NEGV;   // true score of state j after the last step
  int   cur  = 0;

  for (int t = 0; t < len; ++t) {
    bar_lgkm();                          // p(t), Mslot writes now visible
    const int cpos = t & (CH - 1);
    const int rpar = t & 1;

    if (cpos == 0) {                     // chunk boundary (own-wave DMA only)
      wait_vm0();
      cur = (t >> 3) & 1;
      const int tn = t + CH;
      if (tn < len) {
        dma16(hb + (size_t)(tn + (lane >> 3)) * K + 32 * wid + 4 * (lane & 7),
              &hbuf[cur ^ 1][wid][0][0]);
      }
    }

    const float Snext = Mslot[rpar ^ 1];               // S_{t+1} (1 step stale)
    const float hv    = hbuf[cur][j >> 5][cpos][j & 31];

    // 64-wide half-dot over k in [64*half, 64*half+64)
    const float4* p4 = reinterpret_cast<const float4*>(p_lds[rpar] + 64 * half);
    float a0 = 0.f, a1 = 0.f, a2 = 0.f, a3 = 0.f;
#define DOT(n) { float4 pv = p4[n]; \
    a0 += e##n.x * pv.x; a1 += e##n.y * pv.y; \
    a2 += e##n.z * pv.z; a3 += e##n.w * pv.w; }
    DOT(0)  DOT(1)  DOT(2)  DOT(3)  DOT(4)  DOT(5)  DOT(6)  DOT(7)
    DOT(8)  DOT(9)  DOT(10) DOT(11) DOT(12) DOT(13) DOT(14) DOT(15)
#undef DOT
    const float tot = pair_sum((a0 + a1) + (a2 + a3));  // full 128-wide dot

    // off-critical-path factor: g = exp(h + S_t - S_{t+1})
    const float g = __expf(hv + Scur - Snext);
    p_lds[rpar ^ 1][j] = tot * g;                       // both halves, same value

    fs = hv + Scur + __logf(tot);                       // true score_j(t)
    if (tid == 4) Mslot[rpar] = fs;                     // tracker = state j=2
    Scur = Snext;
  }

  // ---- epilogue: out[b] = logsumexp_j(fs_j + trans[EOS, j]) ----
  const float f = fs + tr_eos;
  float m = f;
  #pragma unroll
  for (int off = 32; off > 0; off >>= 1) m = fmaxf(m, __shfl_xor(m, off));
  if (lane == 0) red[wid] = m;
  bar_lgkm();
  const float fm = fmaxf(fmaxf(red[0], red[1]), fmaxf(red[2], red[3]));
  float e = (half == 0) ? __expf(f - fm) : 0.0f;        // de-dup the pair copies
  #pragma unroll
  for (int off = 32; off > 0; off >>= 1) e += __shfl_xor(e, off);
  if (lane == 0) red[4 + wid] = e;
  bar_lgkm();
  if (tid == 0) out[b] = fm + __logf((red[4] + red[5]) + (red[6] + red[7]));
}

extern "C" void kernel_launch(void* const* d_in, const int* in_sizes, int n_in,
                              void* d_out, int out_size, void* d_ws, size_t ws_size,
                              hipStream_t stream) {
  const float* h     = (const float*)d_in[0];  // (B,T,K) fp32
  const float* trans = (const float*)d_in[1];  // (K,K)   fp32
  const float* mask  = (const float*)d_in[2];  // (B,T)   fp32
  float* out = (float*)d_out;                  // (B,)    fp32
  const int B = in_sizes[0] / (T * K);         // 256
  crf_fwd<<<B, 256, 0, stream>>>(h, trans, mask, out);
}